// Round 1
// baseline (766.240 us; speedup 1.0000x reference)
//
#include <hip/hip_runtime.h>

// FeaturePlanes: N=1M points (INDIM=4), P=6 pairs, FDIM=16 channels, S=1025.
// out[n, p*16 + c] = bilinear(fm[p, c, :, :], x=x[n,ii[p]], y=x[n,jj[p]])
// align_corners=True, padding border (inputs are in [-1,1] anyway).

#define FP_S 1025
#define FP_C 16
#define FP_P 6

// ---------------- transpose fm[p][c][y][x] -> fmT[p][y][x][c] ----------------
__global__ __launch_bounds__(256) void fp_transpose(const float* __restrict__ fm,
                                                    float* __restrict__ fmT) {
    const int plane = FP_S * FP_S;
    int idx = blockIdx.x * 256 + threadIdx.x;
    if (idx >= plane) return;
    int p = blockIdx.z;
    int x = idx % FP_S;
    int y = idx / FP_S;

    const float* src = fm + (size_t)p * FP_C * plane + (size_t)y * FP_S + x;
    float v[FP_C];
#pragma unroll
    for (int c = 0; c < FP_C; ++c) v[c] = src[(size_t)c * plane];

    float* dst = fmT + ((size_t)p * plane + (size_t)y * FP_S + x) * FP_C;
#pragma unroll
    for (int k = 0; k < 4; ++k) {
        ((float4*)dst)[k] = make_float4(v[4 * k], v[4 * k + 1], v[4 * k + 2], v[4 * k + 3]);
    }
}

// ---------------- shared coordinate math ----------------
__device__ __forceinline__ void fp_coords(float xv, float yv,
                                          int& x0, int& x1, int& y0, int& y1,
                                          float& w00, float& w01, float& w10, float& w11) {
    float px = fminf(fmaxf((xv + 1.0f) * 512.0f, 0.0f), 1024.0f);
    float py = fminf(fmaxf((yv + 1.0f) * 512.0f, 0.0f), 1024.0f);
    float fx0 = floorf(px), fy0 = floorf(py);
    x0 = (int)fx0;
    y0 = (int)fy0;
    x1 = min(x0 + 1, FP_S - 1);
    y1 = min(y0 + 1, FP_S - 1);
    float wx = px - fx0, wy = py - fy0;
    w00 = (1.0f - wx) * (1.0f - wy);
    w01 = wx * (1.0f - wy);
    w10 = (1.0f - wx) * wy;
    w11 = wx * wy;
}

__device__ __forceinline__ void fp_pair(int p, int& ii, int& jj) {
    // pairs: (0,1),(0,2),(0,3),(1,2),(1,3),(2,3) — p is wave-uniform (blockIdx.z)
    switch (p) {
        case 0: ii = 0; jj = 1; break;
        case 1: ii = 0; jj = 2; break;
        case 2: ii = 0; jj = 3; break;
        case 3: ii = 1; jj = 2; break;
        case 4: ii = 1; jj = 3; break;
        default: ii = 2; jj = 3; break;
    }
}

// ---------------- sample from channel-last fmT ----------------
__global__ __launch_bounds__(256) void fp_sample_t(const float* __restrict__ xin,
                                                   const float* __restrict__ fmT,
                                                   float* __restrict__ out, int N) {
    int n = blockIdx.x * 256 + threadIdx.x;
    if (n >= N) return;
    int p = blockIdx.z;
    int ii, jj;
    fp_pair(p, ii, jj);

    float4 xr = ((const float4*)xin)[n];
    float xv = (ii == 0) ? xr.x : ((ii == 1) ? xr.y : xr.z);  // ii in {0,1,2}
    float yv = (jj == 1) ? xr.y : ((jj == 2) ? xr.z : xr.w);  // jj in {1,2,3}

    int x0, x1, y0, y1;
    float w00, w01, w10, w11;
    fp_coords(xv, yv, x0, x1, y0, y1, w00, w01, w10, w11);

    const size_t plane = (size_t)FP_S * FP_S;
    const float* basep = fmT + (size_t)p * plane * FP_C;
    const float4* c00 = (const float4*)(basep + ((size_t)y0 * FP_S + x0) * FP_C);
    const float4* c01 = (const float4*)(basep + ((size_t)y0 * FP_S + x1) * FP_C);
    const float4* c10 = (const float4*)(basep + ((size_t)y1 * FP_S + x0) * FP_C);
    const float4* c11 = (const float4*)(basep + ((size_t)y1 * FP_S + x1) * FP_C);

    float4* o = (float4*)(out + (size_t)n * (FP_P * FP_C) + p * FP_C);
#pragma unroll
    for (int k = 0; k < 4; ++k) {
        float4 a = c00[k], b = c01[k], g = c10[k], d = c11[k];
        float4 r;
        r.x = a.x * w00 + b.x * w01 + g.x * w10 + d.x * w11;
        r.y = a.y * w00 + b.y * w01 + g.y * w10 + d.y * w11;
        r.z = a.z * w00 + b.z * w01 + g.z * w10 + d.z * w11;
        r.w = a.w * w00 + b.w * w01 + g.w * w10 + d.w * w11;
        o[k] = r;
    }
}

// ---------------- fallback: sample directly from channel-major fm ----------------
__global__ __launch_bounds__(256) void fp_sample_direct(const float* __restrict__ xin,
                                                        const float* __restrict__ fm,
                                                        float* __restrict__ out, int N) {
    int n = blockIdx.x * 256 + threadIdx.x;
    if (n >= N) return;
    int p = blockIdx.z;
    int ii, jj;
    fp_pair(p, ii, jj);

    float4 xr = ((const float4*)xin)[n];
    float xv = (ii == 0) ? xr.x : ((ii == 1) ? xr.y : xr.z);
    float yv = (jj == 1) ? xr.y : ((jj == 2) ? xr.z : xr.w);

    int x0, x1, y0, y1;
    float w00, w01, w10, w11;
    fp_coords(xv, yv, x0, x1, y0, y1, w00, w01, w10, w11);

    const size_t plane = (size_t)FP_S * FP_S;
    const float* pl = fm + (size_t)p * FP_C * plane;
    float res[FP_C];
#pragma unroll
    for (int c = 0; c < FP_C; ++c) {
        const float* plc = pl + (size_t)c * plane;
        float a = plc[(size_t)y0 * FP_S + x0];
        float b = plc[(size_t)y0 * FP_S + x1];
        float g = plc[(size_t)y1 * FP_S + x0];
        float d = plc[(size_t)y1 * FP_S + x1];
        res[c] = a * w00 + b * w01 + g * w10 + d * w11;
    }
    float4* o = (float4*)(out + (size_t)n * (FP_P * FP_C) + p * FP_C);
#pragma unroll
    for (int k = 0; k < 4; ++k)
        o[k] = make_float4(res[4 * k], res[4 * k + 1], res[4 * k + 2], res[4 * k + 3]);
}

extern "C" void kernel_launch(void* const* d_in, const int* in_sizes, int n_in,
                              void* d_out, int out_size, void* d_ws, size_t ws_size,
                              hipStream_t stream) {
    const float* x = (const float*)d_in[0];
    const float* fm = (const float*)d_in[1];
    float* out = (float*)d_out;
    int N = in_sizes[0] / 4;

    const size_t plane = (size_t)FP_S * FP_S;
    const size_t needed = (size_t)FP_P * plane * FP_C * sizeof(float);  // ~403.4 MB

    dim3 gS((unsigned)((N + 255) / 256), 1, FP_P);
    if (ws_size >= needed) {
        float* fmT = (float*)d_ws;
        dim3 gT((unsigned)((plane + 255) / 256), 1, FP_P);
        fp_transpose<<<gT, 256, 0, stream>>>(fm, fmT);
        fp_sample_t<<<gS, 256, 0, stream>>>(x, fmT, out, N);
    } else {
        fp_sample_direct<<<gS, 256, 0, stream>>>(x, fm, out, N);
    }
}

// Round 2
// 571.445 us; speedup vs baseline: 1.3409x; 1.3409x over previous
//
#include <hip/hip_runtime.h>
#include <hip/hip_fp16.h>

// FeaturePlanes: N=1M points (INDIM=4), P=6 pairs, FDIM=16 channels, S=1025.
// out[n, p*16 + c] = bilinear(fm[p, c, :, :], x=x[n,ii[p]], y=x[n,jj[p]])
// Strategy: transpose fm (fp32 channel-major) -> fmT (fp16 channel-LAST,
// [p][y][x][c]) in d_ws. fmT = 202 MB -> fits L3 (256 MB); corner = 32 B.
// Precision budget: threshold 1.0156e-3, fp32-exact showed 1.2e-4; fp16
// texels add <=3e-5 (values |v|<~0.06, convex blend). Safe margin.

#define FP_S 1025
#define FP_C 16
#define FP_P 6

// ------------- transpose+downcast fm[p][c][y][x] fp32 -> fmT[p][y][x][c] fp16 -------------
__global__ __launch_bounds__(256) void fp_transpose_h(const float* __restrict__ fm,
                                                      __half* __restrict__ fmT) {
    const int plane = FP_S * FP_S;
    int idx = blockIdx.x * 256 + threadIdx.x;
    if (idx >= plane) return;
    int p = blockIdx.z;

    // reads: for each c, consecutive threads read consecutive addresses (coalesced)
    const float* src = fm + (size_t)p * FP_C * plane + idx;
    union {
        __half h[FP_C];
        float4 f4[2];
    } u;
#pragma unroll
    for (int c = 0; c < FP_C; ++c) u.h[c] = __float2half(src[(size_t)c * plane]);

    // writes: thread idx writes 32 B at offset idx*32 -> fully coalesced
    float4* dst = (float4*)(fmT + ((size_t)p * plane + idx) * FP_C);
    dst[0] = u.f4[0];
    dst[1] = u.f4[1];
}

// ---------------- shared coordinate math ----------------
__device__ __forceinline__ void fp_coords(float xv, float yv,
                                          int& x0, int& x1, int& y0, int& y1,
                                          float& w00, float& w01, float& w10, float& w11) {
    float px = fminf(fmaxf((xv + 1.0f) * 512.0f, 0.0f), 1024.0f);
    float py = fminf(fmaxf((yv + 1.0f) * 512.0f, 0.0f), 1024.0f);
    float fx0 = floorf(px), fy0 = floorf(py);
    x0 = (int)fx0;
    y0 = (int)fy0;
    x1 = min(x0 + 1, FP_S - 1);
    y1 = min(y0 + 1, FP_S - 1);
    float wx = px - fx0, wy = py - fy0;
    w00 = (1.0f - wx) * (1.0f - wy);
    w01 = wx * (1.0f - wy);
    w10 = (1.0f - wx) * wy;
    w11 = wx * wy;
}

__device__ __forceinline__ void fp_pair(int p, int& ii, int& jj) {
    // pairs: (0,1),(0,2),(0,3),(1,2),(1,3),(2,3) — p is wave-uniform (blockIdx.z)
    switch (p) {
        case 0: ii = 0; jj = 1; break;
        case 1: ii = 0; jj = 2; break;
        case 2: ii = 0; jj = 3; break;
        case 3: ii = 1; jj = 2; break;
        case 4: ii = 1; jj = 3; break;
        default: ii = 2; jj = 3; break;
    }
}

// ---------------- sample from channel-last fp16 fmT ----------------
__global__ __launch_bounds__(256) void fp_sample_h(const float* __restrict__ xin,
                                                   const __half* __restrict__ fmT,
                                                   float* __restrict__ out, int N) {
    int n = blockIdx.x * 256 + threadIdx.x;
    if (n >= N) return;
    int p = blockIdx.z;
    int ii, jj;
    fp_pair(p, ii, jj);

    float4 xr = ((const float4*)xin)[n];
    float xv = (ii == 0) ? xr.x : ((ii == 1) ? xr.y : xr.z);  // ii in {0,1,2}
    float yv = (jj == 1) ? xr.y : ((jj == 2) ? xr.z : xr.w);  // jj in {1,2,3}

    int x0, x1, y0, y1;
    float w00, w01, w10, w11;
    fp_coords(xv, yv, x0, x1, y0, y1, w00, w01, w10, w11);

    const size_t plane = (size_t)FP_S * FP_S;
    const __half* basep = fmT + (size_t)p * plane * FP_C;
    const float4* c00 = (const float4*)(basep + ((size_t)y0 * FP_S + x0) * FP_C);
    const float4* c01 = (const float4*)(basep + ((size_t)y0 * FP_S + x1) * FP_C);
    const float4* c10 = (const float4*)(basep + ((size_t)y1 * FP_S + x0) * FP_C);
    const float4* c11 = (const float4*)(basep + ((size_t)y1 * FP_S + x1) * FP_C);

    // issue all 8 16-B loads, then blend in fp32
    float4 a0 = c00[0], a1 = c00[1];
    float4 b0 = c01[0], b1 = c01[1];
    float4 g0 = c10[0], g1 = c10[1];
    float4 d0 = c11[0], d1 = c11[1];

    float4* o = (float4*)(out + (size_t)n * (FP_P * FP_C) + p * FP_C);

    const __half2* ah = (const __half2*)&a0;  // a0,a1 contiguous? not guaranteed — handle per reg
    (void)ah;

    union {
        float4 f4;
        __half2 h2[4];
    } ua, ub, ug, ud;
    float res[FP_C];
#pragma unroll
    for (int half_idx = 0; half_idx < 2; ++half_idx) {
        ua.f4 = half_idx ? a1 : a0;
        ub.f4 = half_idx ? b1 : b0;
        ug.f4 = half_idx ? g1 : g0;
        ud.f4 = half_idx ? d1 : d0;
#pragma unroll
        for (int q = 0; q < 4; ++q) {
            float2 fa = __half22float2(ua.h2[q]);
            float2 fb = __half22float2(ub.h2[q]);
            float2 fg = __half22float2(ug.h2[q]);
            float2 fd = __half22float2(ud.h2[q]);
            int c = half_idx * 8 + q * 2;
            res[c]     = fa.x * w00 + fb.x * w01 + fg.x * w10 + fd.x * w11;
            res[c + 1] = fa.y * w00 + fb.y * w01 + fg.y * w10 + fd.y * w11;
        }
    }
#pragma unroll
    for (int k = 0; k < 4; ++k)
        o[k] = make_float4(res[4 * k], res[4 * k + 1], res[4 * k + 2], res[4 * k + 3]);
}

// ---------------- fallback: sample directly from channel-major fp32 fm ----------------
__global__ __launch_bounds__(256) void fp_sample_direct(const float* __restrict__ xin,
                                                        const float* __restrict__ fm,
                                                        float* __restrict__ out, int N) {
    int n = blockIdx.x * 256 + threadIdx.x;
    if (n >= N) return;
    int p = blockIdx.z;
    int ii, jj;
    fp_pair(p, ii, jj);

    float4 xr = ((const float4*)xin)[n];
    float xv = (ii == 0) ? xr.x : ((ii == 1) ? xr.y : xr.z);
    float yv = (jj == 1) ? xr.y : ((jj == 2) ? xr.z : xr.w);

    int x0, x1, y0, y1;
    float w00, w01, w10, w11;
    fp_coords(xv, yv, x0, x1, y0, y1, w00, w01, w10, w11);

    const size_t plane = (size_t)FP_S * FP_S;
    const float* pl = fm + (size_t)p * FP_C * plane;
    float res[FP_C];
#pragma unroll
    for (int c = 0; c < FP_C; ++c) {
        const float* plc = pl + (size_t)c * plane;
        float a = plc[(size_t)y0 * FP_S + x0];
        float b = plc[(size_t)y0 * FP_S + x1];
        float g = plc[(size_t)y1 * FP_S + x0];
        float d = plc[(size_t)y1 * FP_S + x1];
        res[c] = a * w00 + b * w01 + g * w10 + d * w11;
    }
    float4* o = (float4*)(out + (size_t)n * (FP_P * FP_C) + p * FP_C);
#pragma unroll
    for (int k = 0; k < 4; ++k)
        o[k] = make_float4(res[4 * k], res[4 * k + 1], res[4 * k + 2], res[4 * k + 3]);
}

extern "C" void kernel_launch(void* const* d_in, const int* in_sizes, int n_in,
                              void* d_out, int out_size, void* d_ws, size_t ws_size,
                              hipStream_t stream) {
    const float* x = (const float*)d_in[0];
    const float* fm = (const float*)d_in[1];
    float* out = (float*)d_out;
    int N = in_sizes[0] / 4;

    const size_t plane = (size_t)FP_S * FP_S;
    const size_t needed = (size_t)FP_P * plane * FP_C * sizeof(__half);  // ~201.7 MB

    dim3 gS((unsigned)((N + 255) / 256), 1, FP_P);
    if (ws_size >= needed) {
        __half* fmT = (__half*)d_ws;
        dim3 gT((unsigned)((plane + 255) / 256), 1, FP_P);
        fp_transpose_h<<<gT, 256, 0, stream>>>(fm, fmT);
        fp_sample_h<<<gS, 256, 0, stream>>>(x, fmT, out, N);
    } else {
        fp_sample_direct<<<gS, 256, 0, stream>>>(x, fm, out, N);
    }
}